// Round 4
// baseline (1091.006 us; speedup 1.0000x reference)
//
#include <hip/hip_runtime.h>

// Problem: B=4, S=2048, D=2048, H=16, hs=128.
// Inputs/outputs fp32 (per reference); internal compute bf16 MFMA.
// d_out (fp32): [0, 16777216) ff_o [B,S,D]; [16777216, 50331648) kv [2,B,H,S,hs]
//   ff_o region is scratch until gemm_ff writes it:
//     phase A (cvt):      Xb bf16 [0,32MiB) + Wpb bf16 [32,56MiB)
//     phase C (repack):   Kb bf16 [0,32MiB) + Vtb bf16 [32,64MiB)  (Xb/Wpb dead)
// d_ws (bf16): [0, 32 MiB) q [64(bh),2048,128] -> overwritten in-place by attn_o;
//   [32 MiB, 40 MiB) W_ff bf16 (only if ws_size permits; else fp32 fallback GEMM).
//
// GEMM swizzle (this round): all bf16 GEMM operands are stored with 16B chunks
// permuted within each 128B span: chunk c at position c ^ (row&7). LDS staging
// stays linear (gld16); ds_read applies the same XOR -> each 8-lane group of a
// ds_read_b128 hits all 32 banks exactly once (conflict-free).

using floatx4 = __attribute__((ext_vector_type(4))) float;
using short8  = __attribute__((ext_vector_type(8))) short;

#define MFMA_BF16(a, b, c) __builtin_amdgcn_mfma_f32_16x16x32_bf16((a), (b), (c), 0, 0, 0)

static __device__ __forceinline__ unsigned short f2bf(float f) {
    unsigned u = __float_as_uint(f);
    u += 0x7FFF + ((u >> 16) & 1);   // round-to-nearest-even
    return (unsigned short)(u >> 16);
}
// load 8 consecutive floats, convert to 8 bf16
static __device__ __forceinline__ short8 cvt8(const float* p) {
    float4 a = ((const float4*)p)[0];
    float4 b = ((const float4*)p)[1];
    short8 r;
    r[0] = (short)f2bf(a.x); r[1] = (short)f2bf(a.y);
    r[2] = (short)f2bf(a.z); r[3] = (short)f2bf(a.w);
    r[4] = (short)f2bf(b.x); r[5] = (short)f2bf(b.y);
    r[6] = (short)f2bf(b.z); r[7] = (short)f2bf(b.w);
    return r;
}

// async global->LDS, 16B per lane. LDS dest = wave-uniform base + lane*16.
static __device__ __forceinline__ void gld16(const void* g, const void* l) {
    unsigned loff = (unsigned)__builtin_amdgcn_readfirstlane((int)(unsigned)(uintptr_t)l);
    __builtin_amdgcn_global_load_lds(
        (__attribute__((address_space(1))) unsigned*)(uintptr_t)g,
        (__attribute__((address_space(3))) unsigned*)loff,
        16, 0, 0);
}

// ---------------------------------------------------------------------------
// cvt: fp32 -> bf16 bulk conversion (X, W_proj, optionally W_ff), writing the
// row-keyed chunk swizzle: 8-elem group c of row r -> position (c&~7)|((c^r)&7).
// All three tensors have 2048 cols = 256 groups/row.
// ---------------------------------------------------------------------------
__global__ __launch_bounds__(256) void cvt_kernel(
    const float* __restrict__ X, const float* __restrict__ Wp,
    const float* __restrict__ Wf,
    unsigned short* __restrict__ Xb, unsigned short* __restrict__ Wpb,
    unsigned short* __restrict__ Wfb, int doWf)
{
    const int NX = 2097152;            // 16,777,216 / 8
    const int NP = 1572864;            // 12,582,912 / 8
    const int NF = 524288;             //  4,194,304 / 8
    const int total = NX + NP + (doWf ? NF : 0);
    const int stride = gridDim.x * 256;
    for (int g = blockIdx.x * 256 + threadIdx.x; g < total; g += stride) {
        const float* src; unsigned short* dst; int off;
        if (g < NX)           { src = X;  dst = Xb;  off = g; }
        else if (g < NX + NP) { src = Wp; dst = Wpb; off = g - NX; }
        else                  { src = Wf; dst = Wfb; off = g - NX - NP; }
        const int row = off >> 8;      // 256 groups per row
        const int c   = off & 255;
        const int dof = (row << 8) | (c & ~7) | ((c ^ row) & 7);
        short8 v = cvt8(src + (size_t)off * 8);
        *(short8*)(dst + (size_t)dof * 8) = v;
    }
}

// ---------------------------------------------------------------------------
// GEMM1 (m97 structure + swizzle): Xb[8192,2048]bf16 @ Wpb[6144,2048]^T + b_proj
//   -> q(bf16 ws, swizzled), k/v(fp32 out). 128x128 tile, BK=64, gld16.
// ---------------------------------------------------------------------------
__global__ __launch_bounds__(256) void gemm_qkv_kernel(
    const unsigned short* __restrict__ Xb,   // [8192, 2048] bf16 swz
    const unsigned short* __restrict__ Wpb,  // [6144, 2048] bf16 swz
    const float* __restrict__ Bias,          // [6144]
    unsigned short* __restrict__ Qws,        // [64, 2048, 128] bf16 swz
    float* __restrict__ KV)                  // [2, 64, 2048, 128] fp32
{
    const int K = 2048;
    __shared__ unsigned short As[128 * 64];  // linear: required by global_load_lds
    __shared__ unsigned short Bs[128 * 64];
    const int n0 = blockIdx.x * 128;
    const int m0 = blockIdx.y * 128;
    const int t = threadIdx.x;
    const int w = t >> 6, l = t & 63;
    const int lr = l & 15, lq = l >> 4;
    const int lr7 = lr & 7;
    const int wr = w >> 1, wc = w & 1;       // wave -> 64x64 quadrant
    const int srow = l >> 3;                 // staging: 8 lanes per 128B row
    const int scol = (l & 7) * 8;

    floatx4 acc[4][4];
#pragma unroll
    for (int mi = 0; mi < 4; ++mi)
#pragma unroll
        for (int ni = 0; ni < 4; ++ni) acc[mi][ni] = (floatx4){0, 0, 0, 0};

    for (int k0 = 0; k0 < K; k0 += 64) {
        __syncthreads();                     // prev compute done with LDS
#pragma unroll
        for (int i = 0; i < 4; ++i) {
            const int rb = (i * 4 + w) * 8;  // 8 rows per wave-issue
            gld16(Xb  + (size_t)(m0 + rb + srow) * K + k0 + scol, &As[(rb)*64]);
            gld16(Wpb + (size_t)(n0 + rb + srow) * K + k0 + scol, &Bs[(rb)*64]);
        }
        __syncthreads();                     // drains vmcnt -> tiles ready
#pragma unroll
        for (int kc = 0; kc < 2; ++kc) {
            short8 af[4], bg[4];
#pragma unroll
            for (int mi = 0; mi < 4; ++mi)
                af[mi] = *(const short8*)
                    &As[(wr * 64 + mi * 16 + lr) * 64 + ((((kc << 2) | lq) ^ lr7) << 3)];
#pragma unroll
            for (int ni = 0; ni < 4; ++ni)
                bg[ni] = *(const short8*)
                    &Bs[(wc * 64 + ni * 16 + lr) * 64 + ((((kc << 2) | lq) ^ lr7) << 3)];
#pragma unroll
            for (int mi = 0; mi < 4; ++mi)
#pragma unroll
                for (int ni = 0; ni < 4; ++ni)
                    acc[mi][ni] = MFMA_BF16(af[mi], bg[ni], acc[mi][ni]);
        }
    }
    // epilogue: row = m0+wr*64+mi*16+lq*4+r, col = n0+wc*64+ni*16+lr (m89 layout)
#pragma unroll
    for (int ni = 0; ni < 4; ++ni) {
        int e = n0 + wc * 64 + ni * 16 + lr;
        int h = e / 384;
        int c = e - h * 384;                 // q[0,128) k[128,256) v[256,384)
        float bias = Bias[e];
#pragma unroll
        for (int mi = 0; mi < 4; ++mi) {
#pragma unroll
            for (int r = 0; r < 4; ++r) {
                int m = m0 + wr * 64 + mi * 16 + lq * 4 + r;
                int b = m >> 11, s = m & 2047;
                float o = acc[mi][ni][r] + bias;
                size_t base = (((size_t)(b * 16 + h)) * 2048 + s) * 128;
                if (c < 128)
                    Qws[base + ((((c >> 3) ^ (s & 7)) << 3) | (c & 7))] = f2bf(o);
                else if (c < 256) KV[base + (c - 128)] = o;
                else              KV[(size_t)16777216 + base + (c - 256)] = o;
            }
        }
    }
}

// ---------------------------------------------------------------------------
// repack_kv: fp32 KV -> bf16 Kb (row-major, chunk-swizzled) + Vtb (transposed,
// chunk-swizzled). Runs ONCE; amortizes cvt+transpose over ~16.5 q-tiles.
// ---------------------------------------------------------------------------
__global__ __launch_bounds__(256) void repack_kv_kernel(
    const float* __restrict__ KV,     // [2,64,2048,128] fp32
    unsigned short* __restrict__ Kb,  // [64][2048][128] bf16 swizzled
    unsigned short* __restrict__ Vtb) // [64][128][2048] bf16 transposed+swizzled
{
    __shared__ short Vt[128][72];
    const int bh = blockIdx.x >> 5;
    const int w  = blockIdx.x & 31;        // 64-key window
    const int t  = threadIdx.x;

    // ---- K: rows s = w*64 .. +63, 16 chunks of 8 elems each ----
    {
        const int kr = t >> 2;             // 0..63
        const int c4 = (t & 3) * 4;        // chunks c4..c4+3
        const int s  = w * 64 + kr;
        const float* kp = KV + ((size_t)bh * 2048 + s) * 128 + c4 * 8;
        unsigned short* ko = Kb + ((size_t)bh * 2048 + s) * 128;
        const int sw = s & 7;
#pragma unroll
        for (int j = 0; j < 4; ++j) {
            short8 v = cvt8(kp + j * 8);
            *(short8*)(ko + ((c4 + j) ^ sw) * 8) = v;
        }
    }

    // ---- V: transpose 64 keys x 128 d via LDS (pair-packed dwords) ----
    {
        const int vkp = t & 31;            // key pair (keys 2vkp, 2vkp+1)
        const int vd0 = (t >> 5) * 16;     // 16-d chunk
        const float* vap = KV + (((size_t)64 + bh) * 2048 + w * 64 + 2 * vkp) * 128 + vd0;
        short8 va0 = cvt8(vap),       va1 = cvt8(vap + 8);
        short8 vb0 = cvt8(vap + 128), vb1 = cvt8(vap + 136);
#pragma unroll
        for (int dd = 0; dd < 8; ++dd) {
            unsigned w0 = (unsigned)(unsigned short)va0[dd] |
                          ((unsigned)(unsigned short)vb0[dd] << 16);
            unsigned w1 = (unsigned)(unsigned short)va1[dd] |
                          ((unsigned)(unsigned short)vb1[dd] << 16);
            *(unsigned*)&Vt[vd0 + dd][2 * vkp]     = w0;
            *(unsigned*)&Vt[vd0 + 8 + dd][2 * vkp] = w1;
        }
    }
    __syncthreads();
    // write out: 2 threads per d-row, 4 chunks of 16B each, swizzled in window
    {
        const int d = t >> 1, hf = t & 1;
        unsigned short* vo = Vtb + ((size_t)bh * 128 + d) * 2048 + w * 64;
        const int dw = d & 7;
#pragma unroll
        for (int j = 0; j < 4; ++j) {
            int c = hf * 4 + j;
            uint4 v = *(const uint4*)&Vt[d][c * 8];
            *(uint4*)(vo + (c ^ dw) * 8) = v;
        }
    }
}

// ---------------------------------------------------------------------------
// Flash attention v3: 4 waves x 16 q-rows = 64 q/block; 64-key kv tiles.
// K/V staged bf16 via global_load_lds (DMA, zero VALU), pre-swizzled source +
// XOR on ds_read (rule 21). Swapped QK^T -> lane-local softmax, 256 threads.
// ---------------------------------------------------------------------------
__global__ __launch_bounds__(256) void attn_kernel(
    unsigned short* __restrict__ QA,        // [64, 2048, 128] bf16 swz: q in, o out
    const unsigned short* __restrict__ Kb,  // [64][2048][128] bf16 swizzled
    const unsigned short* __restrict__ Vtb) // [64][128][2048] bf16 T+swizzled
{
    const int S = 2048;
    __shared__ unsigned short Ks[64 * 128]; // 16 KB linear (gld16 dest)
    __shared__ unsigned short Vt[128 * 64]; // 16 KB linear
    __shared__ short Pb[4][16][72];         //  9 KB

    const int bh = blockIdx.y;
    const int qt = gridDim.x - 1 - blockIdx.x; // heavy blocks first
    const int q0 = qt * 64;
    const int t = threadIdx.x;
    const int wv = t >> 6;
    const int l = t & 63;
    const int lr = l & 15;
    const int lq = l >> 4;
    const int lr7 = lr & 7;

    unsigned short* Qp = QA + ((size_t)bh * S + q0) * 128;
    const unsigned short* gK = Kb + (size_t)bh * S * 128;
    const unsigned short* gV = Vtb + (size_t)bh * 128 * S;

    short8 qf[4];   // Qws is chunk-swizzled by row: chunk ci at ci ^ (q&7), q&7 = lr7
#pragma unroll
    for (int kc = 0; kc < 4; ++kc)
        qf[kc] = *(const short8*)(Qp + (size_t)(wv * 16 + lr) * 128 +
                                  ((((kc << 2) | lq) ^ lr7) << 3));

    float m_i = -1e30f, l_i = 0.0f;
    floatx4 oacc[8];
#pragma unroll
    for (int nt = 0; nt < 8; ++nt) oacc[nt] = (floatx4){0, 0, 0, 0};

    const int ntiles = qt + 1;
    for (int it = 0; it < ntiles; ++it) {
        const int kv0 = it * 64;
        __syncthreads();                    // prev tile's MFMA reads done
        // K tile: contiguous 16 KB; call i+wave wv -> 4 rows (1 KB)
#pragma unroll
        for (int i = 0; i < 4; ++i) {
            const int off = (i * 16 + wv * 4) * 128;         // elements
            gld16(gK + (size_t)kv0 * 128 + off + l * 8, &Ks[off]);
        }
        // V tile: [128 d][64 keys] = 16 KB; global rows strided 4096 B
#pragma unroll
        for (int i = 0; i < 4; ++i) {
            const int ob = (i * 16 + wv * 4) * 256 + l * 16; // byte in tile
            const int d = ob >> 7, rem = ob & 127;
            gld16((const char*)gV + (size_t)d * (S * 2) + kv0 * 2 + rem,
                  (const char*)Vt + (i * 16 + wv * 4) * 256);
        }
        __syncthreads();                    // drains vmcnt -> tiles ready

        // ---- QK^T swapped: sacc[mt] = S^T (rows=key, cols=q) ----
        floatx4 sacc[4];
#pragma unroll
        for (int mt = 0; mt < 4; ++mt) sacc[mt] = (floatx4){0, 0, 0, 0};
#pragma unroll
        for (int kc = 0; kc < 4; ++kc) {
#pragma unroll
            for (int mt = 0; mt < 4; ++mt) {
                short8 a = *(const short8*)
                    &Ks[(mt * 16 + lr) * 128 + ((((kc << 2) | lq) ^ lr7) << 3)];
                sacc[mt] = MFMA_BF16(a, qf[kc], sacc[mt]);
            }
        }

        // ---- mask + online softmax, all 64 lanes ----
        float sv[16];
        const bool diag = (it == qt);
#pragma unroll
        for (int mt = 0; mt < 4; ++mt)
#pragma unroll
            for (int r = 0; r < 4; ++r) {
                float x = sacc[mt][r] * 0.08838834764831845f;
                if (diag && (mt * 16 + lq * 4 + r > wv * 16 + lr)) x = -1e30f;
                sv[mt * 4 + r] = x;
            }
        float mx = sv[0];
#pragma unroll
        for (int j = 1; j < 16; ++j) mx = fmaxf(mx, sv[j]);
        mx = fmaxf(mx, __shfl_xor(mx, 16));
        mx = fmaxf(mx, __shfl_xor(mx, 32));
        float m_new = fmaxf(m_i, mx);
        float alpha = __expf(m_i - m_new);
        m_i = m_new;
        float sum = 0.0f;
        unsigned pw[8];
#pragma unroll
        for (int j = 0; j < 8; ++j) {
            float p0 = __expf(sv[2 * j]     - m_new);
            float p1 = __expf(sv[2 * j + 1] - m_new);
            sum += p0 + p1;
            pw[j] = (unsigned)f2bf(p0) | ((unsigned)f2bf(p1) << 16);
        }
        sum += __shfl_xor(sum, 16);
        sum += __shfl_xor(sum, 32);
        l_i = l_i * alpha + sum;

#pragma unroll
        for (int mt = 0; mt < 4; ++mt)
            *(uint2*)&Pb[wv][lr][mt * 16 + lq * 4] =
                make_uint2(pw[2 * mt], pw[2 * mt + 1]);

        // ---- rescale O, then PV ----
        float am[4];
#pragma unroll
        for (int r = 0; r < 4; ++r) am[r] = __shfl(alpha, lq * 4 + r);
#pragma unroll
        for (int nt = 0; nt < 8; ++nt)
#pragma unroll
            for (int r = 0; r < 4; ++r) oacc[nt][r] *= am[r];

        short8 pa0 = *(const short8*)&Pb[wv][lr][lq * 8];        // keys  0..31
        short8 pa1 = *(const short8*)&Pb[wv][lr][32 + lq * 8];   // keys 32..63
#pragma unroll
        for (int nt = 0; nt < 8; ++nt) {
            const int row = nt * 16 + lr;
            short8 v0 = *(const short8*)&Vt[row * 64 + ((lq ^ lr7) << 3)];
            short8 v1 = *(const short8*)&Vt[row * 64 + (((4 + lq) ^ lr7) << 3)];
            oacc[nt] = MFMA_BF16(pa0, v0, oacc[nt]);
            oacc[nt] = MFMA_BF16(pa1, v1, oacc[nt]);
        }
    }

    float lm[4];
#pragma unroll
    for (int r = 0; r < 4; ++r) lm[r] = 1.0f / __shfl(l_i, lq * 4 + r);
    // O write: element e=nt*16+lr of row q stored at swizzled chunk (e>>3)^(q&7)
#pragma unroll
    for (int nt = 0; nt < 8; ++nt) {
#pragma unroll
        for (int r = 0; r < 4; ++r) {
            int q = wv * 16 + lq * 4 + r;
            int ch = (nt * 2 + (lr >> 3)) ^ (q & 7);
            Qp[(size_t)q * 128 + (ch << 3) + (lr & 7)] = f2bf(oacc[nt][r] * lm[r]);
        }
    }
}

// ---------------------------------------------------------------------------
// GEMM2 (m97 structure + swizzle): attn_o(bf16 swz ws) @ Wfb[2048,2048]^T + b_ff
// ---------------------------------------------------------------------------
__global__ __launch_bounds__(256) void gemm_ff_kernel(
    const unsigned short* __restrict__ AOhm,  // [64, 2048, 128] bf16 swz
    const unsigned short* __restrict__ Wfb,   // [2048, 2048] bf16 swz
    const float* __restrict__ Bias,           // [2048]
    float* __restrict__ Out)                  // [8192, 2048]
{
    const int K = 2048;
    __shared__ unsigned short As[128 * 64];
    __shared__ unsigned short Bs[128 * 64];
    const int n0 = blockIdx.x * 128;
    const int m0 = blockIdx.y * 128;
    const int t = threadIdx.x;
    const int w = t >> 6, l = t & 63;
    const int lr = l & 15, lq = l >> 4;
    const int lr7 = lr & 7;
    const int wr = w >> 1, wc = w & 1;
    const int srow = l >> 3;
    const int scol = (l & 7) * 8;

    floatx4 acc[4][4];
#pragma unroll
    for (int mi = 0; mi < 4; ++mi)
#pragma unroll
        for (int ni = 0; ni < 4; ++ni) acc[mi][ni] = (floatx4){0, 0, 0, 0};

    for (int k0 = 0; k0 < K; k0 += 64) {
        const int h = k0 >> 7, d0 = (k0 & 127) + scol;  // 64 | 128: tile in one head
        __syncthreads();
#pragma unroll
        for (int i = 0; i < 4; ++i) {
            const int rb = (i * 4 + w) * 8;
            const int m = m0 + rb + srow;
            const int b = m >> 11, s = m & 2047;
            gld16(AOhm + ((size_t)(b * 16 + h) * 2048 + s) * 128 + d0, &As[(rb)*64]);
            gld16(Wfb  + (size_t)(n0 + rb + srow) * K + k0 + scol,     &Bs[(rb)*64]);
        }
        __syncthreads();
#pragma unroll
        for (int kc = 0; kc < 2; ++kc) {
            short8 af[4], bg[4];
#pragma unroll
            for (int mi = 0; mi < 4; ++mi)
                af[mi] = *(const short8*)
                    &As[(wr * 64 + mi * 16 + lr) * 64 + ((((kc << 2) | lq) ^ lr7) << 3)];
#pragma unroll
            for (int ni = 0; ni < 4; ++ni)
                bg[ni] = *(const short8*)
                    &Bs[(wc * 64 + ni * 16 + lr) * 64 + ((((kc << 2) | lq) ^ lr7) << 3)];
#pragma unroll
            for (int mi = 0; mi < 4; ++mi)
#pragma unroll
                for (int ni = 0; ni < 4; ++ni)
                    acc[mi][ni] = MFMA_BF16(af[mi], bg[ni], acc[mi][ni]);
        }
    }
#pragma unroll
    for (int ni = 0; ni < 4; ++ni) {
        int e = n0 + wc * 64 + ni * 16 + lr;
        float bias = Bias[e];
#pragma unroll
        for (int mi = 0; mi < 4; ++mi) {
#pragma unroll
            for (int r = 0; r < 4; ++r) {
                int m = m0 + wr * 64 + mi * 16 + lq * 4 + r;
                Out[(size_t)m * 2048 + e] = acc[mi][ni][r] + bias;
            }
        }
    }
}

// ---------------------------------------------------------------------------
// GEMM2 fallback (64^2, fp32 W staging) if ws can't hold Wfb.
// A (AOhm) is chunk-swizzled: de-swizzle on load, LDS stays logical.
// ---------------------------------------------------------------------------
__global__ __launch_bounds__(256) void gemm_ff_fb_kernel(
    const unsigned short* __restrict__ AOhm,  // [64, 2048, 128] bf16 swz
    const float* __restrict__ W,              // [2048, 2048]
    const float* __restrict__ Bias,           // [2048]
    float* __restrict__ Out)                  // [8192, 2048]
{
    const int K = 2048;
    __shared__ short As[64][72];
    __shared__ short Bs[64][72];
    const int n0 = blockIdx.x * 64;
    const int m0 = blockIdx.y * 64;
    const int t = threadIdx.x;
    const int wv = t >> 6;
    const int l = t & 63;
    const int lr = l & 15;
    const int lq = l >> 4;
    const int srow = t >> 2;
    const int scol = (t & 3) << 4;

    floatx4 acc[4] = {{0,0,0,0},{0,0,0,0},{0,0,0,0},{0,0,0,0}};

    const int mrow = m0 + srow;
    const int b = mrow >> 11, s = mrow & 2047;
    const int sw = s & 7;
    const unsigned short* gA = AOhm + (size_t)(b * 16) * 262144 + (size_t)s * 128;
    const float* gB = W + (size_t)(n0 + srow) * K + scol;

    for (int k0 = 0; k0 < K; k0 += 64) {
        int kk = k0 + scol;
        int h = kk >> 7, d = kk & 127;
        int span = (d >> 6) * 64;
        int c0 = (d >> 3) & 7;                 // even
        const unsigned short* pa = gA + (size_t)h * 262144 + span;
        uint4 av0 = *(const uint4*)(pa + ((c0 ^ sw) << 3));
        uint4 av1 = *(const uint4*)(pa + (((c0 + 1) ^ sw) << 3));
        short8 b0 = cvt8(gB + k0);
        short8 b1 = cvt8(gB + k0 + 8);
        __syncthreads();
        *(uint4*)&As[srow][scol]      = av0;
        *(uint4*)&As[srow][scol + 8]  = av1;
        *(short8*)&Bs[srow][scol]     = b0;
        *(short8*)&Bs[srow][scol + 8] = b1;
        __syncthreads();
#pragma unroll
        for (int kc = 0; kc < 2; ++kc) {
            short8 a = *(const short8*)&As[wv * 16 + lr][kc * 32 + lq * 8];
#pragma unroll
            for (int j = 0; j < 4; ++j) {
                short8 b2 = *(const short8*)&Bs[j * 16 + lr][kc * 32 + lq * 8];
                acc[j] = MFMA_BF16(a, b2, acc[j]);
            }
        }
    }
#pragma unroll
    for (int j = 0; j < 4; ++j) {
        int e = n0 + j * 16 + lr;
        float bias = Bias[e];
#pragma unroll
        for (int r = 0; r < 4; ++r) {
            int m = m0 + wv * 16 + lq * 4 + r;
            Out[(size_t)m * 2048 + e] = acc[j][r] + bias;
        }
    }
}

extern "C" void kernel_launch(void* const* d_in, const int* in_sizes, int n_in,
                              void* d_out, int out_size, void* d_ws, size_t ws_size,
                              hipStream_t stream) {
    const float* X  = (const float*)d_in[0];  // x
    const float* Wp = (const float*)d_in[1];  // w_proj
    const float* bp = (const float*)d_in[2];  // b_proj
    const float* Wf = (const float*)d_in[3];  // w_ff
    const float* bf = (const float*)d_in[4];  // b_ff

    float* out = (float*)d_out;
    float* kv  = out + 16777216;              // next_prefix_kv [2,4,16,2048,128] fp32
    unsigned short* Qws = (unsigned short*)d_ws; // q -> attn_o in-place, 32 MiB

    // phase A scratch (out[0,56MiB)): Xb + Wpb
    unsigned short* Xb  = (unsigned short*)out;       // 32 MiB
    unsigned short* Wpb = Xb + 16777216;              // 24 MiB
    // phase C scratch (out[0,64MiB), Xb/Wpb dead after gemm_qkv): Kb + Vtb
    unsigned short* Kbs = (unsigned short*)out;       // 32 MiB
    unsigned short* Vtb = Kbs + 16777216;             // 32 MiB
    const bool wfInWs = ws_size >= (size_t)33554432 + 8388608;
    unsigned short* Wfb = wfInWs ? Qws + 16777216 : (unsigned short*)nullptr;

    cvt_kernel<<<dim3(2048), 256, 0, stream>>>(X, Wp, Wf, Xb, Wpb, Wfb,
                                               wfInWs ? 1 : 0);
    gemm_qkv_kernel<<<dim3(48, 64), 256, 0, stream>>>(Xb, Wpb, bp, Qws, kv);
    repack_kv_kernel<<<dim3(2048), 256, 0, stream>>>(kv, Kbs, Vtb);
    attn_kernel<<<dim3(32, 64), 256, 0, stream>>>(Qws, Kbs, Vtb);
    if (wfInWs)
        gemm_ff_kernel<<<dim3(16, 64), 256, 0, stream>>>(Qws, Wfb, bf, out);
    else
        gemm_ff_fb_kernel<<<dim3(32, 128), 256, 0, stream>>>(Qws, Wf, bf, out);
}

// Round 5
// 962.392 us; speedup vs baseline: 1.1336x; 1.1336x over previous
//
#include <hip/hip_runtime.h>

// Problem: B=4, S=2048, D=2048, H=16, hs=128.
// Inputs/outputs fp32 (per reference); internal compute bf16 MFMA.
// d_out (fp32): [0, 16777216) ff_o [B,S,D]; [16777216, 50331648) kv [2,B,H,S,hs]
//   ff_o region is scratch until gemm_ff writes it:
//     phase A (cvt):      Xb bf16 [0,32MiB) + Wpb bf16 [32,56MiB)
//     phase C (repack):   Kb bf16 [0,32MiB) + Vtb bf16 [32,64MiB)  (Xb/Wpb dead)
// d_ws (bf16): [0, 32 MiB) q [64(bh),2048,128] -> overwritten in-place by attn_o.
//
// Swizzle: bf16 GEMM/attn operands stored with 16B chunks permuted within each
// 128B span: chunk c at position c ^ (row&7). LDS staging stays linear (gld16);
// ds_read applies the same XOR -> conflict-free b128 fragment reads.

using floatx4 = __attribute__((ext_vector_type(4))) float;
using short8  = __attribute__((ext_vector_type(8))) short;

#define MFMA_BF16(a, b, c) __builtin_amdgcn_mfma_f32_16x16x32_bf16((a), (b), (c), 0, 0, 0)

static __device__ __forceinline__ unsigned short f2bf(float f) {
    unsigned u = __float_as_uint(f);
    u += 0x7FFF + ((u >> 16) & 1);   // round-to-nearest-even
    return (unsigned short)(u >> 16);
}
// load 8 consecutive floats, convert to 8 bf16
static __device__ __forceinline__ short8 cvt8(const float* p) {
    float4 a = ((const float4*)p)[0];
    float4 b = ((const float4*)p)[1];
    short8 r;
    r[0] = (short)f2bf(a.x); r[1] = (short)f2bf(a.y);
    r[2] = (short)f2bf(a.z); r[3] = (short)f2bf(a.w);
    r[4] = (short)f2bf(b.x); r[5] = (short)f2bf(b.y);
    r[6] = (short)f2bf(b.z); r[7] = (short)f2bf(b.w);
    return r;
}

// async global->LDS, 16B per lane. LDS dest = wave-uniform base + lane*16.
static __device__ __forceinline__ void gld16(const void* g, const void* l) {
    unsigned loff = (unsigned)__builtin_amdgcn_readfirstlane((int)(unsigned)(uintptr_t)l);
    __builtin_amdgcn_global_load_lds(
        (__attribute__((address_space(1))) unsigned*)(uintptr_t)g,
        (__attribute__((address_space(3))) unsigned*)loff,
        16, 0, 0);
}

// ---------------------------------------------------------------------------
// cvt: fp32 -> bf16 bulk conversion (X, W_proj), row-keyed chunk swizzle:
// 8-elem group c of row r -> position (c&~7)|((c^r)&7). 2048 cols = 256 grp/row.
// ---------------------------------------------------------------------------
__global__ __launch_bounds__(256) void cvt_kernel(
    const float* __restrict__ X, const float* __restrict__ Wp,
    unsigned short* __restrict__ Xb, unsigned short* __restrict__ Wpb)
{
    const int NX = 2097152;            // 16,777,216 / 8
    const int NP = 1572864;            // 12,582,912 / 8
    const int total = NX + NP;
    const int stride = gridDim.x * 256;
    for (int g = blockIdx.x * 256 + threadIdx.x; g < total; g += stride) {
        const float* src; unsigned short* dst; int off;
        if (g < NX) { src = X;  dst = Xb;  off = g; }
        else        { src = Wp; dst = Wpb; off = g - NX; }
        const int row = off >> 8;      // 256 groups per row
        const int c   = off & 255;
        const int dof = (row << 8) | (c & ~7) | ((c ^ row) & 7);
        short8 v = cvt8(src + (size_t)off * 8);
        *(short8*)(dst + (size_t)dof * 8) = v;
    }
}

// ---------------------------------------------------------------------------
// GEMM1 (m97 structure + swizzle): Xb[8192,2048]bf16 @ Wpb[6144,2048]^T + b_proj
//   -> q(bf16 ws, swizzled), k/v(fp32 out). 128x128 tile, BK=64, gld16.
// ---------------------------------------------------------------------------
__global__ __launch_bounds__(256) void gemm_qkv_kernel(
    const unsigned short* __restrict__ Xb,   // [8192, 2048] bf16 swz
    const unsigned short* __restrict__ Wpb,  // [6144, 2048] bf16 swz
    const float* __restrict__ Bias,          // [6144]
    unsigned short* __restrict__ Qws,        // [64, 2048, 128] bf16 swz
    float* __restrict__ KV)                  // [2, 64, 2048, 128] fp32
{
    const int K = 2048;
    __shared__ unsigned short As[128 * 64];  // linear: required by global_load_lds
    __shared__ unsigned short Bs[128 * 64];
    const int n0 = blockIdx.x * 128;
    const int m0 = blockIdx.y * 128;
    const int t = threadIdx.x;
    const int w = t >> 6, l = t & 63;
    const int lr = l & 15, lq = l >> 4;
    const int lr7 = lr & 7;
    const int wr = w >> 1, wc = w & 1;       // wave -> 64x64 quadrant
    const int srow = l >> 3;                 // staging: 8 lanes per 128B row
    const int scol = (l & 7) * 8;

    floatx4 acc[4][4];
#pragma unroll
    for (int mi = 0; mi < 4; ++mi)
#pragma unroll
        for (int ni = 0; ni < 4; ++ni) acc[mi][ni] = (floatx4){0, 0, 0, 0};

    for (int k0 = 0; k0 < K; k0 += 64) {
        __syncthreads();                     // prev compute done with LDS
#pragma unroll
        for (int i = 0; i < 4; ++i) {
            const int rb = (i * 4 + w) * 8;  // 8 rows per wave-issue
            gld16(Xb  + (size_t)(m0 + rb + srow) * K + k0 + scol, &As[(rb)*64]);
            gld16(Wpb + (size_t)(n0 + rb + srow) * K + k0 + scol, &Bs[(rb)*64]);
        }
        __syncthreads();                     // drains vmcnt -> tiles ready
#pragma unroll
        for (int kc = 0; kc < 2; ++kc) {
            short8 af[4], bg[4];
#pragma unroll
            for (int mi = 0; mi < 4; ++mi)
                af[mi] = *(const short8*)
                    &As[(wr * 64 + mi * 16 + lr) * 64 + ((((kc << 2) | lq) ^ lr7) << 3)];
#pragma unroll
            for (int ni = 0; ni < 4; ++ni)
                bg[ni] = *(const short8*)
                    &Bs[(wc * 64 + ni * 16 + lr) * 64 + ((((kc << 2) | lq) ^ lr7) << 3)];
#pragma unroll
            for (int mi = 0; mi < 4; ++mi)
#pragma unroll
                for (int ni = 0; ni < 4; ++ni)
                    acc[mi][ni] = MFMA_BF16(af[mi], bg[ni], acc[mi][ni]);
        }
    }
    // epilogue: row = m0+wr*64+mi*16+lq*4+r, col = n0+wc*64+ni*16+lr (m89 layout)
#pragma unroll
    for (int ni = 0; ni < 4; ++ni) {
        int e = n0 + wc * 64 + ni * 16 + lr;
        int h = e / 384;
        int c = e - h * 384;                 // q[0,128) k[128,256) v[256,384)
        float bias = Bias[e];
#pragma unroll
        for (int mi = 0; mi < 4; ++mi) {
#pragma unroll
            for (int r = 0; r < 4; ++r) {
                int m = m0 + wr * 64 + mi * 16 + lq * 4 + r;
                int b = m >> 11, s = m & 2047;
                float o = acc[mi][ni][r] + bias;
                size_t base = (((size_t)(b * 16 + h)) * 2048 + s) * 128;
                if (c < 128)
                    Qws[base + ((((c >> 3) ^ (s & 7)) << 3) | (c & 7))] = f2bf(o);
                else if (c < 256) KV[base + (c - 128)] = o;
                else              KV[(size_t)16777216 + base + (c - 256)] = o;
            }
        }
    }
}

// ---------------------------------------------------------------------------
// repack_kv: fp32 KV -> bf16 Kb (row-major, chunk-swizzled) + Vtb (transposed,
// chunk-swizzled). Runs ONCE; amortizes cvt+transpose over ~16.5 q-tiles.
// ---------------------------------------------------------------------------
__global__ __launch_bounds__(256) void repack_kv_kernel(
    const float* __restrict__ KV,     // [2,64,2048,128] fp32
    unsigned short* __restrict__ Kb,  // [64][2048][128] bf16 swizzled
    unsigned short* __restrict__ Vtb) // [64][128][2048] bf16 transposed+swizzled
{
    __shared__ short Vt[128][72];
    const int bh = blockIdx.x >> 5;
    const int w  = blockIdx.x & 31;        // 64-key window
    const int t  = threadIdx.x;

    // ---- K: rows s = w*64 .. +63, 16 chunks of 8 elems each ----
    {
        const int kr = t >> 2;             // 0..63
        const int c4 = (t & 3) * 4;        // chunks c4..c4+3
        const int s  = w * 64 + kr;
        const float* kp = KV + ((size_t)bh * 2048 + s) * 128 + c4 * 8;
        unsigned short* ko = Kb + ((size_t)bh * 2048 + s) * 128;
        const int sw = s & 7;
#pragma unroll
        for (int j = 0; j < 4; ++j) {
            short8 v = cvt8(kp + j * 8);
            *(short8*)(ko + ((c4 + j) ^ sw) * 8) = v;
        }
    }

    // ---- V: transpose 64 keys x 128 d via LDS (pair-packed dwords) ----
    {
        const int vkp = t & 31;            // key pair (keys 2vkp, 2vkp+1)
        const int vd0 = (t >> 5) * 16;     // 16-d chunk
        const float* vap = KV + (((size_t)64 + bh) * 2048 + w * 64 + 2 * vkp) * 128 + vd0;
        short8 va0 = cvt8(vap),       va1 = cvt8(vap + 8);
        short8 vb0 = cvt8(vap + 128), vb1 = cvt8(vap + 136);
#pragma unroll
        for (int dd = 0; dd < 8; ++dd) {
            unsigned w0 = (unsigned)(unsigned short)va0[dd] |
                          ((unsigned)(unsigned short)vb0[dd] << 16);
            unsigned w1 = (unsigned)(unsigned short)va1[dd] |
                          ((unsigned)(unsigned short)vb1[dd] << 16);
            *(unsigned*)&Vt[vd0 + dd][2 * vkp]     = w0;
            *(unsigned*)&Vt[vd0 + 8 + dd][2 * vkp] = w1;
        }
    }
    __syncthreads();
    // write out: 2 threads per d-row, 4 chunks of 16B each, swizzled in window
    {
        const int d = t >> 1, hf = t & 1;
        unsigned short* vo = Vtb + ((size_t)bh * 128 + d) * 2048 + w * 64;
        const int dw = d & 7;
#pragma unroll
        for (int j = 0; j < 4; ++j) {
            int c = hf * 4 + j;
            uint4 v = *(const uint4*)&Vt[d][c * 8];
            *(uint4*)(vo + (c ^ dw) * 8) = v;
        }
    }
}

// ---------------------------------------------------------------------------
// Flash attention v4: double-buffered K/V + ONE barrier per tile (T3-minimum).
// barrier(tile t landed) -> issue STAGE(t+1) -> compute(t): load latency hides
// under compute. 4 waves x 16 q-rows; 64-key tiles; swapped QK^T softmax.
// ---------------------------------------------------------------------------
__global__ __launch_bounds__(256) void attn_kernel(
    unsigned short* __restrict__ QA,        // [64, 2048, 128] bf16 swz: q in, o out
    const unsigned short* __restrict__ Kb,  // [64][2048][128] bf16 swizzled
    const unsigned short* __restrict__ Vtb) // [64][128][2048] bf16 T+swizzled
{
    const int S = 2048;
    __shared__ unsigned short Ks[2][64 * 128]; // 2 x 16 KB (gld16 dest, linear)
    __shared__ unsigned short Vt[2][128 * 64]; // 2 x 16 KB
    __shared__ short Pb[4][16][72];            // 9 KB  (total 74 KB -> 2 blk/CU)

    const int bh = blockIdx.y;
    const int qt = gridDim.x - 1 - blockIdx.x; // heavy blocks first
    const int q0 = qt * 64;
    const int t = threadIdx.x;
    const int wv = t >> 6;
    const int l = t & 63;
    const int lr = l & 15;
    const int lq = l >> 4;
    const int lr7 = lr & 7;

    unsigned short* Qp = QA + ((size_t)bh * S + q0) * 128;
    const unsigned short* gK = Kb + (size_t)bh * S * 128;
    const unsigned short* gV = Vtb + (size_t)bh * 128 * S;

    short8 qf[4];   // Qws chunk-swizzled by row: chunk ci at ci ^ (q&7), q&7 = lr7
#pragma unroll
    for (int kc = 0; kc < 4; ++kc)
        qf[kc] = *(const short8*)(Qp + (size_t)(wv * 16 + lr) * 128 +
                                  ((((kc << 2) | lq) ^ lr7) << 3));

    float m_i = -1e30f, l_i = 0.0f;
    floatx4 oacc[8];
#pragma unroll
    for (int nt = 0; nt < 8; ++nt) oacc[nt] = (floatx4){0, 0, 0, 0};

    const int ntiles = qt + 1;

    // STAGE(buf, tile): 8 gld16 per wave; K 16 KB + V 16 KB
#define STAGE(BUF, KV0)                                                        \
    {                                                                          \
        const int kv0_ = (KV0);                                                \
        _Pragma("unroll")                                                      \
        for (int i = 0; i < 4; ++i) {                                          \
            const int off = (i * 16 + wv * 4) * 128;                           \
            gld16(gK + (size_t)kv0_ * 128 + off + l * 8, &Ks[BUF][off]);       \
        }                                                                      \
        _Pragma("unroll")                                                      \
        for (int i = 0; i < 4; ++i) {                                          \
            const int ob = (i * 16 + wv * 4) * 256 + l * 16;                   \
            const int d = ob >> 7, rem = ob & 127;                             \
            gld16((const char*)gV + (size_t)d * (S * 2) + kv0_ * 2 + rem,      \
                  (const char*)&Vt[BUF][0] + (i * 16 + wv * 4) * 256);         \
        }                                                                      \
    }

    STAGE(0, 0);                            // prologue: tile 0 into buf 0

    for (int it = 0; it < ntiles; ++it) {
        const int cur = it & 1;
        __syncthreads();                    // drains vmcnt: tile `it` landed in
                                            // buf[cur]; buf[cur^1] free (it-1 done)
        if (it + 1 < ntiles) STAGE(cur ^ 1, (it + 1) * 64);

        const unsigned short* Kc = &Ks[cur][0];
        const unsigned short* Vc = &Vt[cur][0];

        // ---- QK^T swapped: sacc[mt] = S^T (rows=key, cols=q) ----
        floatx4 sacc[4];
#pragma unroll
        for (int mt = 0; mt < 4; ++mt) sacc[mt] = (floatx4){0, 0, 0, 0};
#pragma unroll
        for (int kc = 0; kc < 4; ++kc) {
#pragma unroll
            for (int mt = 0; mt < 4; ++mt) {
                short8 a = *(const short8*)
                    &Kc[(mt * 16 + lr) * 128 + ((((kc << 2) | lq) ^ lr7) << 3)];
                sacc[mt] = MFMA_BF16(a, qf[kc], sacc[mt]);
            }
        }

        // ---- mask + online softmax, all 64 lanes ----
        float sv[16];
        const bool diag = (it == qt);
#pragma unroll
        for (int mt = 0; mt < 4; ++mt)
#pragma unroll
            for (int r = 0; r < 4; ++r) {
                float x = sacc[mt][r] * 0.08838834764831845f;
                if (diag && (mt * 16 + lq * 4 + r > wv * 16 + lr)) x = -1e30f;
                sv[mt * 4 + r] = x;
            }
        float mx = sv[0];
#pragma unroll
        for (int j = 1; j < 16; ++j) mx = fmaxf(mx, sv[j]);
        mx = fmaxf(mx, __shfl_xor(mx, 16));
        mx = fmaxf(mx, __shfl_xor(mx, 32));
        float m_new = fmaxf(m_i, mx);
        float alpha = __expf(m_i - m_new);
        m_i = m_new;
        float sum = 0.0f;
        unsigned pw[8];
#pragma unroll
        for (int j = 0; j < 8; ++j) {
            float p0 = __expf(sv[2 * j]     - m_new);
            float p1 = __expf(sv[2 * j + 1] - m_new);
            sum += p0 + p1;
            pw[j] = (unsigned)f2bf(p0) | ((unsigned)f2bf(p1) << 16);
        }
        sum += __shfl_xor(sum, 16);
        sum += __shfl_xor(sum, 32);
        l_i = l_i * alpha + sum;

#pragma unroll
        for (int mt = 0; mt < 4; ++mt)
            *(uint2*)&Pb[wv][lr][mt * 16 + lq * 4] =
                make_uint2(pw[2 * mt], pw[2 * mt + 1]);

        // ---- rescale O, then PV ----
        float am[4];
#pragma unroll
        for (int r = 0; r < 4; ++r) am[r] = __shfl(alpha, lq * 4 + r);
#pragma unroll
        for (int nt = 0; nt < 8; ++nt)
#pragma unroll
            for (int r = 0; r < 4; ++r) oacc[nt][r] *= am[r];

        short8 pa0 = *(const short8*)&Pb[wv][lr][lq * 8];        // keys  0..31
        short8 pa1 = *(const short8*)&Pb[wv][lr][32 + lq * 8];   // keys 32..63
#pragma unroll
        for (int nt = 0; nt < 8; ++nt) {
            const int row = nt * 16 + lr;
            short8 v0 = *(const short8*)&Vc[row * 64 + ((lq ^ lr7) << 3)];
            short8 v1 = *(const short8*)&Vc[row * 64 + (((4 + lq) ^ lr7) << 3)];
            oacc[nt] = MFMA_BF16(pa0, v0, oacc[nt]);
            oacc[nt] = MFMA_BF16(pa1, v1, oacc[nt]);
        }
    }
#undef STAGE

    float lm[4];
#pragma unroll
    for (int r = 0; r < 4; ++r) lm[r] = 1.0f / __shfl(l_i, lq * 4 + r);
    // O write: element e=nt*16+lr of row q stored at swizzled chunk (e>>3)^(q&7)
#pragma unroll
    for (int nt = 0; nt < 8; ++nt) {
#pragma unroll
        for (int r = 0; r < 4; ++r) {
            int q = wv * 16 + lq * 4 + r;
            int ch = (nt * 2 + (lr >> 3)) ^ (q & 7);
            Qp[(size_t)q * 128 + (ch << 3) + (lr & 7)] = f2bf(oacc[nt][r] * lm[r]);
        }
    }
}

// ---------------------------------------------------------------------------
// GEMM2 v2 (unified, no ws dependency): attn_o(bf16 swz ws) @ w_ff^T + b_ff.
// 128x128 tile; A via gld16 (swizzled Qws); B reg-staged from fp32 W with
// cvt8 + swizzled ds_write (conflict-free fragment reads on both operands).
// ---------------------------------------------------------------------------
__global__ __launch_bounds__(256) void gemm_ff_kernel(
    const unsigned short* __restrict__ AOhm,  // [64, 2048, 128] bf16 swz
    const float* __restrict__ W,              // [2048, 2048] fp32
    const float* __restrict__ Bias,           // [2048]
    float* __restrict__ Out)                  // [8192, 2048]
{
    const int K = 2048;
    __shared__ unsigned short As[128 * 64];
    __shared__ unsigned short Bs[128 * 64];
    const int n0 = blockIdx.x * 128;
    const int m0 = blockIdx.y * 128;
    const int t = threadIdx.x;
    const int w = t >> 6, l = t & 63;
    const int lr = l & 15, lq = l >> 4;
    const int lr7 = lr & 7;
    const int wr = w >> 1, wc = w & 1;
    const int srow = l >> 3;
    const int scol = (l & 7) * 8;

    // B staging: thread -> W row n0+(t>>1), 32-col half (t&1)
    const int brow = t >> 1;
    const int bch0 = (t & 1) * 4;            // first of 4 16B chunks
    const int bsw  = brow & 7;
    const float* gB = W + (size_t)(n0 + brow) * K + bch0 * 8;

    floatx4 acc[4][4];
#pragma unroll
    for (int mi = 0; mi < 4; ++mi)
#pragma unroll
        for (int ni = 0; ni < 4; ++ni) acc[mi][ni] = (floatx4){0, 0, 0, 0};

    for (int k0 = 0; k0 < K; k0 += 64) {
        // B: fp32 global reads + cvt in regs (before barrier: overlap prev MFMA)
        short8 bc[4];
#pragma unroll
        for (int j = 0; j < 4; ++j) bc[j] = cvt8(gB + k0 + j * 8);

        const int h = k0 >> 7, d0 = (k0 & 127) + scol;  // 64 | 128: in one head
        __syncthreads();                      // prev compute done with LDS
#pragma unroll
        for (int i = 0; i < 4; ++i) {
            const int rb = (i * 4 + w) * 8;
            const int m = m0 + rb + srow;
            const int b = m >> 11, s = m & 2047;
            gld16(AOhm + ((size_t)(b * 16 + h) * 2048 + s) * 128 + d0, &As[(rb)*64]);
        }
#pragma unroll
        for (int j = 0; j < 4; ++j)
            *(short8*)&Bs[brow * 64 + (((bch0 + j) ^ bsw) << 3)] = bc[j];
        __syncthreads();                      // drain vmcnt + lgkm -> tiles ready
#pragma unroll
        for (int kc = 0; kc < 2; ++kc) {
            short8 af[4], bg[4];
#pragma unroll
            for (int mi = 0; mi < 4; ++mi)
                af[mi] = *(const short8*)
                    &As[(wr * 64 + mi * 16 + lr) * 64 + ((((kc << 2) | lq) ^ lr7) << 3)];
#pragma unroll
            for (int ni = 0; ni < 4; ++ni)
                bg[ni] = *(const short8*)
                    &Bs[(wc * 64 + ni * 16 + lr) * 64 + ((((kc << 2) | lq) ^ lr7) << 3)];
#pragma unroll
            for (int mi = 0; mi < 4; ++mi)
#pragma unroll
                for (int ni = 0; ni < 4; ++ni)
                    acc[mi][ni] = MFMA_BF16(af[mi], bg[ni], acc[mi][ni]);
        }
    }
#pragma unroll
    for (int ni = 0; ni < 4; ++ni) {
        int e = n0 + wc * 64 + ni * 16 + lr;
        float bias = Bias[e];
#pragma unroll
        for (int mi = 0; mi < 4; ++mi) {
#pragma unroll
            for (int r = 0; r < 4; ++r) {
                int m = m0 + wr * 64 + mi * 16 + lq * 4 + r;
                Out[(size_t)m * 2048 + e] = acc[mi][ni][r] + bias;
            }
        }
    }
}

extern "C" void kernel_launch(void* const* d_in, const int* in_sizes, int n_in,
                              void* d_out, int out_size, void* d_ws, size_t ws_size,
                              hipStream_t stream) {
    const float* X  = (const float*)d_in[0];  // x
    const float* Wp = (const float*)d_in[1];  // w_proj
    const float* bp = (const float*)d_in[2];  // b_proj
    const float* Wf = (const float*)d_in[3];  // w_ff
    const float* bf = (const float*)d_in[4];  // b_ff

    float* out = (float*)d_out;
    float* kv  = out + 16777216;              // next_prefix_kv [2,4,16,2048,128] fp32
    unsigned short* Qws = (unsigned short*)d_ws; // q -> attn_o in-place, 32 MiB

    // phase A scratch (out[0,56MiB)): Xb + Wpb
    unsigned short* Xb  = (unsigned short*)out;       // 32 MiB
    unsigned short* Wpb = Xb + 16777216;              // 24 MiB
    // phase C scratch (out[0,64MiB), Xb/Wpb dead after gemm_qkv): Kb + Vtb
    unsigned short* Kbs = (unsigned short*)out;       // 32 MiB
    unsigned short* Vtb = Kbs + 16777216;             // 32 MiB

    cvt_kernel<<<dim3(2048), 256, 0, stream>>>(X, Wp, Xb, Wpb);
    gemm_qkv_kernel<<<dim3(48, 64), 256, 0, stream>>>(Xb, Wpb, bp, Qws, kv);
    repack_kv_kernel<<<dim3(2048), 256, 0, stream>>>(kv, Kbs, Vtb);
    attn_kernel<<<dim3(32, 64), 256, 0, stream>>>(Qws, Kbs, Vtb);
    gemm_ff_kernel<<<dim3(16, 64), 256, 0, stream>>>(Qws, Wf, bf, out);
}

// Round 6
// 887.764 us; speedup vs baseline: 1.2289x; 1.0841x over previous
//
#include <hip/hip_runtime.h>
#include <hip/hip_bf16.h>

// Problem: B=4, S=2048, D=2048, H=16, hs=128.
// Inputs/outputs fp32 (per reference); internal compute bf16 MFMA.
// d_out (fp32): [0, 16777216) ff_o [B,S,D]; [16777216, 50331648) kv [2,B,H,S,hs]
//   ff_o region is scratch until gemm_ff writes it:
//     phase A (cvt):      Xb bf16 [0,32MiB) + Wpb bf16 [32,56MiB)
//     phase C (repack):   Kb bf16 [0,32MiB) + Vtb bf16 [32,64MiB)  (Xb/Wpb dead)
// d_ws (bf16): [0, 32 MiB) q [64(bh),2048,128] -> overwritten in-place by attn_o;
//   [32 MiB, 40 MiB) W_ff bf16 (only if ws_size permits; else reg-staged fallback).
//
// Swizzle: bf16 GEMM/attn operands stored with 16B chunks permuted within each
// 128B span: chunk c at position c ^ (row&7). LDS staging stays linear (gld16);
// ds_read applies the same XOR -> conflict-free b128 fragment reads.

using floatx4 = __attribute__((ext_vector_type(4))) float;
using short8  = __attribute__((ext_vector_type(8))) short;

#define MFMA_BF16(a, b, c) __builtin_amdgcn_mfma_f32_16x16x32_bf16((a), (b), (c), 0, 0, 0)

static __device__ __forceinline__ unsigned short f2bf(float f) {
    unsigned u = __float_as_uint(f);
    u += 0x7FFF + ((u >> 16) & 1);   // round-to-nearest-even
    return (unsigned short)(u >> 16);
}
// packed RNE f32x2 -> bf16x2 (compiler emits v_cvt_pk_bf16_f32); lo in [15:0]
static __device__ __forceinline__ unsigned cvtpk(float lo, float hi) {
    union { __hip_bfloat162 h; unsigned u; } r;
    r.h = __float22bfloat162_rn(make_float2(lo, hi));
    return r.u;
}
// load 8 consecutive floats, convert to 8 bf16
static __device__ __forceinline__ short8 cvt8(const float* p) {
    float4 a = ((const float4*)p)[0];
    float4 b = ((const float4*)p)[1];
    union { unsigned u[4]; short8 s; } r;
    r.u[0] = cvtpk(a.x, a.y); r.u[1] = cvtpk(a.z, a.w);
    r.u[2] = cvtpk(b.x, b.y); r.u[3] = cvtpk(b.z, b.w);
    return r.s;
}

// async global->LDS, 16B per lane. LDS dest = wave-uniform base + lane*16.
static __device__ __forceinline__ void gld16(const void* g, const void* l) {
    unsigned loff = (unsigned)__builtin_amdgcn_readfirstlane((int)(unsigned)(uintptr_t)l);
    __builtin_amdgcn_global_load_lds(
        (__attribute__((address_space(1))) unsigned*)(uintptr_t)g,
        (__attribute__((address_space(3))) unsigned*)loff,
        16, 0, 0);
}

// ---------------------------------------------------------------------------
// cvt: fp32 -> bf16 bulk conversion (X, W_proj, optionally W_ff), row-keyed
// chunk swizzle: group c of row r -> (c&~7)|((c^r)&7). 2048 cols = 256 grp/row.
// ---------------------------------------------------------------------------
__global__ __launch_bounds__(256) void cvt_kernel(
    const float* __restrict__ X, const float* __restrict__ Wp,
    const float* __restrict__ Wf,
    unsigned short* __restrict__ Xb, unsigned short* __restrict__ Wpb,
    unsigned short* __restrict__ Wfb, int doWf)
{
    const int NX = 2097152;            // 16,777,216 / 8
    const int NP = 1572864;            // 12,582,912 / 8
    const int NF = 524288;             //  4,194,304 / 8
    const int total = NX + NP + (doWf ? NF : 0);
    const int stride = gridDim.x * 256;
    for (int g = blockIdx.x * 256 + threadIdx.x; g < total; g += stride) {
        const float* src; unsigned short* dst; int off;
        if (g < NX)           { src = X;  dst = Xb;  off = g; }
        else if (g < NX + NP) { src = Wp; dst = Wpb; off = g - NX; }
        else                  { src = Wf; dst = Wfb; off = g - NX - NP; }
        const int row = off >> 8;      // 256 groups per row
        const int c   = off & 255;
        const int dof = (row << 8) | (c & ~7) | ((c ^ row) & 7);
        short8 v = cvt8(src + (size_t)off * 8);
        *(short8*)(dst + (size_t)dof * 8) = v;
    }
}

// ---------------------------------------------------------------------------
// GEMM1 (m97 structure + swizzle): Xb[8192,2048]bf16 @ Wpb[6144,2048]^T + b_proj
//   -> q(bf16 ws, swizzled), k/v(fp32 out). 128x128 tile, BK=64, gld16.
// ---------------------------------------------------------------------------
__global__ __launch_bounds__(256) void gemm_qkv_kernel(
    const unsigned short* __restrict__ Xb,   // [8192, 2048] bf16 swz
    const unsigned short* __restrict__ Wpb,  // [6144, 2048] bf16 swz
    const float* __restrict__ Bias,          // [6144]
    unsigned short* __restrict__ Qws,        // [64, 2048, 128] bf16 swz
    float* __restrict__ KV)                  // [2, 64, 2048, 128] fp32
{
    const int K = 2048;
    __shared__ unsigned short As[128 * 64];  // linear: required by global_load_lds
    __shared__ unsigned short Bs[128 * 64];
    const int n0 = blockIdx.x * 128;
    const int m0 = blockIdx.y * 128;
    const int t = threadIdx.x;
    const int w = t >> 6, l = t & 63;
    const int lr = l & 15, lq = l >> 4;
    const int lr7 = lr & 7;
    const int wr = w >> 1, wc = w & 1;       // wave -> 64x64 quadrant
    const int srow = l >> 3;                 // staging: 8 lanes per 128B row
    const int scol = (l & 7) * 8;

    floatx4 acc[4][4];
#pragma unroll
    for (int mi = 0; mi < 4; ++mi)
#pragma unroll
        for (int ni = 0; ni < 4; ++ni) acc[mi][ni] = (floatx4){0, 0, 0, 0};

    for (int k0 = 0; k0 < K; k0 += 64) {
        __syncthreads();                     // prev compute done with LDS
#pragma unroll
        for (int i = 0; i < 4; ++i) {
            const int rb = (i * 4 + w) * 8;  // 8 rows per wave-issue
            gld16(Xb  + (size_t)(m0 + rb + srow) * K + k0 + scol, &As[(rb)*64]);
            gld16(Wpb + (size_t)(n0 + rb + srow) * K + k0 + scol, &Bs[(rb)*64]);
        }
        __syncthreads();                     // drains vmcnt -> tiles ready
#pragma unroll
        for (int kc = 0; kc < 2; ++kc) {
            short8 af[4], bg[4];
#pragma unroll
            for (int mi = 0; mi < 4; ++mi)
                af[mi] = *(const short8*)
                    &As[(wr * 64 + mi * 16 + lr) * 64 + ((((kc << 2) | lq) ^ lr7) << 3)];
#pragma unroll
            for (int ni = 0; ni < 4; ++ni)
                bg[ni] = *(const short8*)
                    &Bs[(wc * 64 + ni * 16 + lr) * 64 + ((((kc << 2) | lq) ^ lr7) << 3)];
#pragma unroll
            for (int mi = 0; mi < 4; ++mi)
#pragma unroll
                for (int ni = 0; ni < 4; ++ni)
                    acc[mi][ni] = MFMA_BF16(af[mi], bg[ni], acc[mi][ni]);
        }
    }
    // epilogue: row = m0+wr*64+mi*16+lq*4+r, col = n0+wc*64+ni*16+lr (m89 layout)
#pragma unroll
    for (int ni = 0; ni < 4; ++ni) {
        int e = n0 + wc * 64 + ni * 16 + lr;
        int h = e / 384;
        int c = e - h * 384;                 // q[0,128) k[128,256) v[256,384)
        float bias = Bias[e];
#pragma unroll
        for (int mi = 0; mi < 4; ++mi) {
#pragma unroll
            for (int r = 0; r < 4; ++r) {
                int m = m0 + wr * 64 + mi * 16 + lq * 4 + r;
                int b = m >> 11, s = m & 2047;
                float o = acc[mi][ni][r] + bias;
                size_t base = (((size_t)(b * 16 + h)) * 2048 + s) * 128;
                if (c < 128)
                    Qws[base + ((((c >> 3) ^ (s & 7)) << 3) | (c & 7))] = f2bf(o);
                else if (c < 256) KV[base + (c - 128)] = o;
                else              KV[(size_t)16777216 + base + (c - 256)] = o;
            }
        }
    }
}

// ---------------------------------------------------------------------------
// repack_kv: fp32 KV -> bf16 Kb (row-major, chunk-swizzled) + Vtb (transposed,
// chunk-swizzled). Runs ONCE; amortizes cvt+transpose over ~16.5 q-tiles.
// ---------------------------------------------------------------------------
__global__ __launch_bounds__(256) void repack_kv_kernel(
    const float* __restrict__ KV,     // [2,64,2048,128] fp32
    unsigned short* __restrict__ Kb,  // [64][2048][128] bf16 swizzled
    unsigned short* __restrict__ Vtb) // [64][128][2048] bf16 transposed+swizzled
{
    __shared__ short Vt[128][72];
    const int bh = blockIdx.x >> 5;
    const int w  = blockIdx.x & 31;        // 64-key window
    const int t  = threadIdx.x;

    // ---- K: rows s = w*64 .. +63, 16 chunks of 8 elems each ----
    {
        const int kr = t >> 2;             // 0..63
        const int c4 = (t & 3) * 4;        // chunks c4..c4+3
        const int s  = w * 64 + kr;
        const float* kp = KV + ((size_t)bh * 2048 + s) * 128 + c4 * 8;
        unsigned short* ko = Kb + ((size_t)bh * 2048 + s) * 128;
        const int sw = s & 7;
#pragma unroll
        for (int j = 0; j < 4; ++j) {
            short8 v = cvt8(kp + j * 8);
            *(short8*)(ko + ((c4 + j) ^ sw) * 8) = v;
        }
    }

    // ---- V: transpose 64 keys x 128 d via LDS (pair-packed dwords) ----
    {
        const int vkp = t & 31;            // key pair (keys 2vkp, 2vkp+1)
        const int vd0 = (t >> 5) * 16;     // 16-d chunk
        const float* vap = KV + (((size_t)64 + bh) * 2048 + w * 64 + 2 * vkp) * 128 + vd0;
        short8 va0 = cvt8(vap),       va1 = cvt8(vap + 8);
        short8 vb0 = cvt8(vap + 128), vb1 = cvt8(vap + 136);
#pragma unroll
        for (int dd = 0; dd < 8; ++dd) {
            unsigned w0 = (unsigned)(unsigned short)va0[dd] |
                          ((unsigned)(unsigned short)vb0[dd] << 16);
            unsigned w1 = (unsigned)(unsigned short)va1[dd] |
                          ((unsigned)(unsigned short)vb1[dd] << 16);
            *(unsigned*)&Vt[vd0 + dd][2 * vkp]     = w0;
            *(unsigned*)&Vt[vd0 + 8 + dd][2 * vkp] = w1;
        }
    }
    __syncthreads();
    // write out: 2 threads per d-row, 4 chunks of 16B each, swizzled in window
    {
        const int d = t >> 1, hf = t & 1;
        unsigned short* vo = Vtb + ((size_t)bh * 128 + d) * 2048 + w * 64;
        const int dw = d & 7;
#pragma unroll
        for (int j = 0; j < 4; ++j) {
            int c = hf * 4 + j;
            uint4 v = *(const uint4*)&Vt[d][c * 8];
            *(uint4*)(vo + (c ^ dw) * 8) = v;
        }
    }
}

// ---------------------------------------------------------------------------
// Flash attention v5: double-buffered K/V + ONE barrier per tile; T13 defer-max
// (skip O-rescale when tile max <= m+8, wave-uniform); cvt_pk P packing;
// pointer-incremented STAGE addressing. 4 waves x 16 q-rows; 64-key tiles.
// ---------------------------------------------------------------------------
__global__ __launch_bounds__(256) void attn_kernel(
    unsigned short* __restrict__ QA,        // [64, 2048, 128] bf16 swz: q in, o out
    const unsigned short* __restrict__ Kb,  // [64][2048][128] bf16 swizzled
    const unsigned short* __restrict__ Vtb) // [64][128][2048] bf16 T+swizzled
{
    const int S = 2048;
    __shared__ unsigned short Ks[2][64 * 128]; // 2 x 16 KB (gld16 dest, linear)
    __shared__ unsigned short Vt[2][128 * 64]; // 2 x 16 KB
    __shared__ short Pb[4][16][72];            // 9 KB  (total 74 KB -> 2 blk/CU)

    const int bh = blockIdx.y;
    const int qt = gridDim.x - 1 - blockIdx.x; // heavy blocks first
    const int q0 = qt * 64;
    const int t = threadIdx.x;
    const int wv = t >> 6;
    const int l = t & 63;
    const int lr = l & 15;
    const int lq = l >> 4;
    const int lr7 = lr & 7;

    unsigned short* Qp = QA + ((size_t)bh * S + q0) * 128;
    const unsigned short* gK = Kb + (size_t)bh * S * 128;
    const unsigned short* gV = Vtb + (size_t)bh * 128 * S;

    short8 qf[4];   // Qws chunk-swizzled by row: chunk ci at ci ^ (q&7), q&7 = lr7
#pragma unroll
    for (int kc = 0; kc < 4; ++kc)
        qf[kc] = *(const short8*)(Qp + (size_t)(wv * 16 + lr) * 128 +
                                  ((((kc << 2) | lq) ^ lr7) << 3));

    float m_i = -1e30f, l_i = 0.0f;
    floatx4 oacc[8];
#pragma unroll
    for (int nt = 0; nt < 8; ++nt) oacc[nt] = (floatx4){0, 0, 0, 0};

    // per-lane staging bases; per-tile advance: K +8192 elems, V +128 bytes
    const unsigned short* gKl = gK + l * 8;
    const char* gVl = (const char*)gV + (size_t)((l >> 3) * 4096 + (l & 7) * 16);
    size_t tK = 0, tV = 0;

#define STAGE(BUF)                                                             \
    {                                                                          \
        _Pragma("unroll")                                                      \
        for (int i = 0; i < 4; ++i) {                                          \
            const int off = (i * 16 + wv * 4) * 128;                           \
            gld16(gKl + tK + off, &Ks[BUF][off]);                              \
        }                                                                      \
        _Pragma("unroll")                                                      \
        for (int i = 0; i < 4; ++i) {                                          \
            const int vb = (i * 32 + wv * 8) * 4096;                           \
            gld16(gVl + tV + vb,                                               \
                  (const char*)&Vt[BUF][0] + (i * 16 + wv * 4) * 256);         \
        }                                                                      \
    }

    const int ntiles = qt + 1;
    STAGE(0);                               // prologue: tile 0 into buf 0
    tK += 8192; tV += 128;

    for (int it = 0; it < ntiles; ++it) {
        const int cur = it & 1;
        __syncthreads();                    // drains vmcnt: tile `it` landed in
                                            // buf[cur]; buf[cur^1] free (it-1 done)
        if (it + 1 < ntiles) { STAGE(cur ^ 1); tK += 8192; tV += 128; }

        const unsigned short* Kc = &Ks[cur][0];
        const unsigned short* Vc = &Vt[cur][0];

        // ---- QK^T swapped: sacc[mt] = S^T (rows=key, cols=q) ----
        floatx4 sacc[4];
#pragma unroll
        for (int mt = 0; mt < 4; ++mt) sacc[mt] = (floatx4){0, 0, 0, 0};
#pragma unroll
        for (int kc = 0; kc < 4; ++kc) {
#pragma unroll
            for (int mt = 0; mt < 4; ++mt) {
                short8 a = *(const short8*)
                    &Kc[(mt * 16 + lr) * 128 + ((((kc << 2) | lq) ^ lr7) << 3)];
                sacc[mt] = MFMA_BF16(a, qf[kc], sacc[mt]);
            }
        }

        // ---- mask + online softmax (defer-max), all 64 lanes ----
        float sv[16];
        const bool diag = (it == qt);
#pragma unroll
        for (int mt = 0; mt < 4; ++mt)
#pragma unroll
            for (int r = 0; r < 4; ++r) {
                float x = sacc[mt][r] * 0.08838834764831845f;
                if (diag && (mt * 16 + lq * 4 + r > wv * 16 + lr)) x = -1e30f;
                sv[mt * 4 + r] = x;
            }
        float mx = sv[0];
#pragma unroll
        for (int j = 1; j < 16; ++j) mx = fmaxf(mx, sv[j]);
        mx = fmaxf(mx, __shfl_xor(mx, 16));
        mx = fmaxf(mx, __shfl_xor(mx, 32));
        const bool nores = __all(mx <= m_i + 8.0f) != 0;   // T13, THR=8
        float alpha = 1.0f;
        if (!nores) {
            float m_new = fmaxf(m_i, mx);
            alpha = __expf(m_i - m_new);
            m_i = m_new;
            float am[4];
#pragma unroll
            for (int r = 0; r < 4; ++r) am[r] = __shfl(alpha, lq * 4 + r);
#pragma unroll
            for (int nt = 0; nt < 8; ++nt)
#pragma unroll
                for (int r = 0; r < 4; ++r) oacc[nt][r] *= am[r];
        }
        float sum = 0.0f;
        unsigned pw[8];
#pragma unroll
        for (int j = 0; j < 8; ++j) {
            float p0 = __expf(sv[2 * j]     - m_i);
            float p1 = __expf(sv[2 * j + 1] - m_i);
            sum += p0 + p1;
            pw[j] = cvtpk(p0, p1);          // v_cvt_pk_bf16_f32
        }
        sum += __shfl_xor(sum, 16);
        sum += __shfl_xor(sum, 32);
        l_i = l_i * alpha + sum;

#pragma unroll
        for (int mt = 0; mt < 4; ++mt)
            *(uint2*)&Pb[wv][lr][mt * 16 + lq * 4] =
                make_uint2(pw[2 * mt], pw[2 * mt + 1]);

        // ---- PV ----
        short8 pa0 = *(const short8*)&Pb[wv][lr][lq * 8];        // keys  0..31
        short8 pa1 = *(const short8*)&Pb[wv][lr][32 + lq * 8];   // keys 32..63
#pragma unroll
        for (int nt = 0; nt < 8; ++nt) {
            const int row = nt * 16 + lr;
            short8 v0 = *(const short8*)&Vc[row * 64 + ((lq ^ lr7) << 3)];
            short8 v1 = *(const short8*)&Vc[row * 64 + (((4 + lq) ^ lr7) << 3)];
            oacc[nt] = MFMA_BF16(pa0, v0, oacc[nt]);
            oacc[nt] = MFMA_BF16(pa1, v1, oacc[nt]);
        }
    }
#undef STAGE

    float lm[4];
#pragma unroll
    for (int r = 0; r < 4; ++r) lm[r] = 1.0f / __shfl(l_i, lq * 4 + r);
    // O write: element e=nt*16+lr of row q stored at swizzled chunk (e>>3)^(q&7)
#pragma unroll
    for (int nt = 0; nt < 8; ++nt) {
#pragma unroll
        for (int r = 0; r < 4; ++r) {
            int q = wv * 16 + lq * 4 + r;
            int ch = (nt * 2 + (lr >> 3)) ^ (q & 7);
            Qp[(size_t)q * 128 + (ch << 3) + (lr & 7)] = f2bf(oacc[nt][r] * lm[r]);
        }
    }
}

// ---------------------------------------------------------------------------
// GEMM2 fast (m97 structure + swizzle): attn_o(bf16 swz ws) @ Wfb^T + b_ff.
// Both operands via gld16 from swizzled bf16 globals.
// ---------------------------------------------------------------------------
__global__ __launch_bounds__(256) void gemm_ff_kernel(
    const unsigned short* __restrict__ AOhm,  // [64, 2048, 128] bf16 swz
    const unsigned short* __restrict__ Wfb,   // [2048, 2048] bf16 swz
    const float* __restrict__ Bias,           // [2048]
    float* __restrict__ Out)                  // [8192, 2048]
{
    const int K = 2048;
    __shared__ unsigned short As[128 * 64];
    __shared__ unsigned short Bs[128 * 64];
    const int n0 = blockIdx.x * 128;
    const int m0 = blockIdx.y * 128;
    const int t = threadIdx.x;
    const int w = t >> 6, l = t & 63;
    const int lr = l & 15, lq = l >> 4;
    const int lr7 = lr & 7;
    const int wr = w >> 1, wc = w & 1;
    const int srow = l >> 3;
    const int scol = (l & 7) * 8;

    floatx4 acc[4][4];
#pragma unroll
    for (int mi = 0; mi < 4; ++mi)
#pragma unroll
        for (int ni = 0; ni < 4; ++ni) acc[mi][ni] = (floatx4){0, 0, 0, 0};

    for (int k0 = 0; k0 < K; k0 += 64) {
        const int h = k0 >> 7, d0 = (k0 & 127) + scol;  // 64 | 128: tile in one head
        __syncthreads();
#pragma unroll
        for (int i = 0; i < 4; ++i) {
            const int rb = (i * 4 + w) * 8;
            const int m = m0 + rb + srow;
            const int b = m >> 11, s = m & 2047;
            gld16(AOhm + ((size_t)(b * 16 + h) * 2048 + s) * 128 + d0, &As[(rb)*64]);
            gld16(Wfb  + (size_t)(n0 + rb + srow) * K + k0 + scol,     &Bs[(rb)*64]);
        }
        __syncthreads();
#pragma unroll
        for (int kc = 0; kc < 2; ++kc) {
            short8 af[4], bg[4];
#pragma unroll
            for (int mi = 0; mi < 4; ++mi)
                af[mi] = *(const short8*)
                    &As[(wr * 64 + mi * 16 + lr) * 64 + ((((kc << 2) | lq) ^ lr7) << 3)];
#pragma unroll
            for (int ni = 0; ni < 4; ++ni)
                bg[ni] = *(const short8*)
                    &Bs[(wc * 64 + ni * 16 + lr) * 64 + ((((kc << 2) | lq) ^ lr7) << 3)];
#pragma unroll
            for (int mi = 0; mi < 4; ++mi)
#pragma unroll
                for (int ni = 0; ni < 4; ++ni)
                    acc[mi][ni] = MFMA_BF16(af[mi], bg[ni], acc[mi][ni]);
        }
    }
#pragma unroll
    for (int ni = 0; ni < 4; ++ni) {
        int e = n0 + wc * 64 + ni * 16 + lr;
        float bias = Bias[e];
#pragma unroll
        for (int mi = 0; mi < 4; ++mi) {
#pragma unroll
            for (int r = 0; r < 4; ++r) {
                int m = m0 + wr * 64 + mi * 16 + lq * 4 + r;
                Out[(size_t)m * 2048 + e] = acc[mi][ni][r] + bias;
            }
        }
    }
}

// ---------------------------------------------------------------------------
// GEMM2 fallback (no ws dependency): B reg-staged from fp32 W with cvt +
// swizzled ds_write. Known-correct (round-5 kernel).
// ---------------------------------------------------------------------------
__global__ __launch_bounds__(256) void gemm_ff_fb_kernel(
    const unsigned short* __restrict__ AOhm,  // [64, 2048, 128] bf16 swz
    const float* __restrict__ W,              // [2048, 2048] fp32
    const float* __restrict__ Bias,           // [2048]
    float* __restrict__ Out)                  // [8192, 2048]
{
    const int K = 2048;
    __shared__ unsigned short As[128 * 64];
    __shared__ unsigned short Bs[128 * 64];
    const int n0 = blockIdx.x * 128;
    const int m0 = blockIdx.y * 128;
    const int t = threadIdx.x;
    const int w = t >> 6, l = t & 63;
    const int lr = l & 15, lq = l >> 4;
    const int lr7 = lr & 7;
    const int wr = w >> 1, wc = w & 1;
    const int srow = l >> 3;
    const int scol = (l & 7) * 8;

    const int brow = t >> 1;
    const int bch0 = (t & 1) * 4;
    const int bsw  = brow & 7;
    const float* gB = W + (size_t)(n0 + brow) * K + bch0 * 8;

    floatx4 acc[4][4];
#pragma unroll
    for (int mi = 0; mi < 4; ++mi)
#pragma unroll
        for (int ni = 0; ni < 4; ++ni) acc[mi][ni] = (floatx4){0, 0, 0, 0};

    for (int k0 = 0; k0 < K; k0 += 64) {
        short8 bc[4];
#pragma unroll
        for (int j = 0; j < 4; ++j) bc[j] = cvt8(gB + k0 + j * 8);

        const int h = k0 >> 7, d0 = (k0 & 127) + scol;
        __syncthreads();
#pragma unroll
        for (int i = 0; i < 4; ++i) {
            const int rb = (i * 4 + w) * 8;
            const int m = m0 + rb + srow;
            const int b = m >> 11, s = m & 2047;
            gld16(AOhm + ((size_t)(b * 16 + h) * 2048 + s) * 128 + d0, &As[(rb)*64]);
        }
#pragma unroll
        for (int j = 0; j < 4; ++j)
            *(short8*)&Bs[brow * 64 + (((bch0 + j) ^ bsw) << 3)] = bc[j];
        __syncthreads();
#pragma unroll
        for (int kc = 0; kc < 2; ++kc) {
            short8 af[4], bg[4];
#pragma unroll
            for (int mi = 0; mi < 4; ++mi)
                af[mi] = *(const short8*)
                    &As[(wr * 64 + mi * 16 + lr) * 64 + ((((kc << 2) | lq) ^ lr7) << 3)];
#pragma unroll
            for (int ni = 0; ni < 4; ++ni)
                bg[ni] = *(const short8*)
                    &Bs[(wc * 64 + ni * 16 + lr) * 64 + ((((kc << 2) | lq) ^ lr7) << 3)];
#pragma unroll
            for (int mi = 0; mi < 4; ++mi)
#pragma unroll
                for (int ni = 0; ni < 4; ++ni)
                    acc[mi][ni] = MFMA_BF16(af[mi], bg[ni], acc[mi][ni]);
        }
    }
#pragma unroll
    for (int ni = 0; ni < 4; ++ni) {
        int e = n0 + wc * 64 + ni * 16 + lr;
        float bias = Bias[e];
#pragma unroll
        for (int mi = 0; mi < 4; ++mi) {
#pragma unroll
            for (int r = 0; r < 4; ++r) {
                int m = m0 + wr * 64 + mi * 16 + lq * 4 + r;
                Out[(size_t)m * 2048 + e] = acc[mi][ni][r] + bias;
            }
        }
    }
}

extern "C" void kernel_launch(void* const* d_in, const int* in_sizes, int n_in,
                              void* d_out, int out_size, void* d_ws, size_t ws_size,
                              hipStream_t stream) {
    const float* X  = (const float*)d_in[0];  // x
    const float* Wp = (const float*)d_in[1];  // w_proj
    const float* bp = (const float*)d_in[2];  // b_proj
    const float* Wf = (const float*)d_in[3];  // w_ff
    const float* bf = (const float*)d_in[4];  // b_ff

    float* out = (float*)d_out;
    float* kv  = out + 16777216;              // next_prefix_kv [2,4,16,2048,128] fp32
    unsigned short* Qws = (unsigned short*)d_ws; // q -> attn_o in-place, 32 MiB

    // phase A scratch (out[0,56MiB)): Xb + Wpb
    unsigned short* Xb  = (unsigned short*)out;       // 32 MiB
    unsigned short* Wpb = Xb + 16777216;              // 24 MiB
    // phase C scratch (out[0,64MiB), Xb/Wpb dead after gemm_qkv): Kb + Vtb
    unsigned short* Kbs = (unsigned short*)out;       // 32 MiB
    unsigned short* Vtb = Kbs + 16777216;             // 32 MiB
    const bool wfInWs = ws_size >= (size_t)33554432 + 8388608;
    unsigned short* Wfb = wfInWs ? Qws + 16777216 : (unsigned short*)nullptr;

    cvt_kernel<<<dim3(2048), 256, 0, stream>>>(X, Wp, Wf, Xb, Wpb, Wfb,
                                               wfInWs ? 1 : 0);
    gemm_qkv_kernel<<<dim3(48, 64), 256, 0, stream>>>(Xb, Wpb, bp, Qws, kv);
    repack_kv_kernel<<<dim3(2048), 256, 0, stream>>>(kv, Kbs, Vtb);
    attn_kernel<<<dim3(32, 64), 256, 0, stream>>>(Qws, Kbs, Vtb);
    if (wfInWs)
        gemm_ff_kernel<<<dim3(16, 64), 256, 0, stream>>>(Qws, Wfb, bf, out);
    else
        gemm_ff_fb_kernel<<<dim3(16, 64), 256, 0, stream>>>(Qws, Wf, bf, out);
}